// Round 2
// baseline (786.130 us; speedup 1.0000x reference)
//
#include <hip/hip_runtime.h>

// QuantAttnBlock on gfx950. Inputs/outputs are FLOAT32 (per reference dtypes).
// Strategy: exact-integer bf16 MFMA for QK and PV (quantized values are small
// ints -> exact in bf16, exact fp32 accumulate); hi/lo bf16 split for the
// fp32-valued GN/PV activations and conv weights feeding the 1x1 convs.

#define Bb 4
#define Cc 256
#define Nn 4096
#define NGRP 32

typedef unsigned short u16;
typedef unsigned int   u32;
typedef unsigned char  u8;
typedef __attribute__((ext_vector_type(8))) short bf16x8;
typedef __attribute__((ext_vector_type(4))) float f32x4;

#define MFMA16(a,b,c) __builtin_amdgcn_mfma_f32_16x16x32_bf16((a),(b),(c),0,0,0)

static __device__ __forceinline__ u16 f2bf(float x){
  u32 u = __float_as_uint(x);
  u += 0x7fffu + ((u >> 16) & 1u);
  return (u16)(u >> 16);
}
static __device__ __forceinline__ float bf2f(u16 h){ return __uint_as_float(((u32)h) << 16); }

union U64c { u16 u[4]; uint2 v; };

// ---------------- GroupNorm stats: one block per (b,g) ----------------
__global__ __launch_bounds__(256) void k_gn_stats(const float* __restrict__ x,
                                                  float* __restrict__ mu, float* __restrict__ rs){
  int bg = blockIdx.x;                       // b*32+g ; group = 8 contiguous channels
  const float4* p = (const float4*)(x + (size_t)bg * (8 * Nn));
  float s = 0.f, q = 0.f;
  for (int i = threadIdx.x; i < 8*Nn/4; i += 256){
    float4 v = p[i];
    s += v.x + v.y + v.z + v.w;
    q += v.x*v.x + v.y*v.y + v.z*v.z + v.w*v.w;
  }
  __shared__ float rsum[256], rsq[256];
  rsum[threadIdx.x] = s; rsq[threadIdx.x] = q;
  __syncthreads();
  for (int off = 128; off > 0; off >>= 1){
    if (threadIdx.x < off){ rsum[threadIdx.x] += rsum[threadIdx.x+off]; rsq[threadIdx.x] += rsq[threadIdx.x+off]; }
    __syncthreads();
  }
  if (threadIdx.x == 0){
    const float inv = 1.0f / (8*Nn);
    float m = rsum[0]*inv;
    float var = rsq[0]*inv - m*m;
    mu[bg] = m; rs[bg] = rsqrtf(var + 1e-6f);
  }
}

// ------------- GroupNorm apply + transpose -> hT hi/lo [b][n][c] -------------
// 64n x 64c tile per block.
__global__ __launch_bounds__(256) void k_gn_apply(const float* __restrict__ x,
                                                  const float* __restrict__ gsc, const float* __restrict__ gbi,
                                                  const float* __restrict__ mu, const float* __restrict__ rs,
                                                  u16* __restrict__ hhi, u16* __restrict__ hlo){
  int nt = blockIdx.x, ct = blockIdx.y, b = blockIdx.z;
  int n0 = nt*64, c0 = ct*64;
  __shared__ float yt[64*65];
  __shared__ float sa[64], sb[64];
  int t = threadIdx.x;
  if (t < 64){
    int c = c0 + t;
    int bg = b*NGRP + (c >> 3);
    float a = rs[bg] * gsc[c];
    sa[t] = a;
    sb[t] = gbi[c] - mu[bg]*a;
  }
  __syncthreads();
  #pragma unroll
  for (int j = 0; j < 4; ++j){
    int id = t + j*256;                      // 0..1023 float4s
    int r = id >> 4, cq = id & 15;
    float4 v = *(const float4*)(x + ((size_t)b*Cc + c0 + r)*Nn + n0 + cq*4);
    float a = sa[r], bb = sb[r];
    yt[r*65 + cq*4 + 0] = v.x*a + bb;
    yt[r*65 + cq*4 + 1] = v.y*a + bb;
    yt[r*65 + cq*4 + 2] = v.z*a + bb;
    yt[r*65 + cq*4 + 3] = v.w*a + bb;
  }
  __syncthreads();
  int nl = t >> 2, cg = (t & 3) * 16;
  size_t base = ((size_t)b*Nn + n0 + nl)*Cc + c0 + cg;
  #pragma unroll
  for (int half = 0; half < 2; ++half){
    union { u16 u[8]; uint4 v; } Ph, Pl;
    #pragma unroll
    for (int u = 0; u < 8; ++u){
      float y = yt[(cg + half*8 + u)*65 + nl];
      u16 h = f2bf(y);
      Ph.u[u] = h; Pl.u[u] = f2bf(y - bf2f(h));
    }
    *(uint4*)(hhi + base + half*8) = Ph.v;
    *(uint4*)(hlo + base + half*8) = Pl.v;
  }
}

// ------------- 1x1 conv GEMM: out[o][n] = sum_c W[o][c] * H[c][n] (+bias) -------------
// W f32 -> hi/lo bf16 fragments; H supplied as hi+lo bf16. 3 MFMAs/k-step ~= fp32.
// mode 0: fake-quant, store transposed bf16 ints (q,k). mode 1: fake-quant, store natural (v).
// mode 2: residual + bias, store f32 to d_out (proj).
__global__ __launch_bounds__(256) void k_conv(const float* __restrict__ W,
                                              const u16* __restrict__ Hhi, const u16* __restrict__ Hlo,
                                              const float* __restrict__ bias,
                                              const float* __restrict__ pd, const float* __restrict__ pz,
                                              u16* __restrict__ outT, u16* __restrict__ outN,
                                              const float* __restrict__ xres, float* __restrict__ outF,
                                              int mode){
  int nt = blockIdx.x, ot = blockIdx.y, b = blockIdx.z;
  __shared__ u16 Lh[64*128], Ll[64*128];
  int t = threadIdx.x, lane = t & 63, wave = t >> 6;
  int lo16 = lane & 15, quad = lane >> 4;
  int o0 = ot*64 + wave*16;

  bf16x8 awh[8], awl[8];
  {
    const float* wb = W + (size_t)(o0 + lo16) * 256;
    #pragma unroll
    for (int k = 0; k < 8; ++k){
      union { u16 u[8]; bf16x8 v; } Wh, Wl;
      #pragma unroll
      for (int u = 0; u < 8; ++u){
        float w = wb[k*32 + quad*8 + u];
        u16 h = f2bf(w);
        Wh.u[u] = h; Wl.u[u] = f2bf(w - bf2f(h));
      }
      awh[k] = Wh.v; awl[k] = Wl.v;
    }
  }
  f32x4 zf = {0.f,0.f,0.f,0.f};
  f32x4 acc[4] = {zf, zf, zf, zf};

  const u16* hb = Hhi + ((size_t)b*Nn + nt*64) * 256;
  const u16* lb = Hlo + ((size_t)b*Nn + nt*64) * 256;
  for (int kc = 0; kc < 2; ++kc){
    __syncthreads();
    for (int id = t; id < 64*16; id += 256){
      int r = id >> 4, ch = id & 15;
      int sw = (ch ^ (r & 7)) * 8;
      *(uint4*)(Lh + r*128 + sw) = *(const uint4*)(hb + (size_t)r*256 + kc*128 + ch*8);
      *(uint4*)(Ll + r*128 + sw) = *(const uint4*)(lb + (size_t)r*256 + kc*128 + ch*8);
    }
    __syncthreads();
    #pragma unroll
    for (int k4 = 0; k4 < 4; ++k4){
      int k = kc*4 + k4;
      #pragma unroll
      for (int ns = 0; ns < 4; ++ns){
        int r = ns*16 + lo16;
        int ch = ((k4*4 + quad) ^ (r & 7)) * 8;
        bf16x8 bh = *(const bf16x8*)(Lh + r*128 + ch);
        bf16x8 bl = *(const bf16x8*)(Ll + r*128 + ch);
        acc[ns] = MFMA16(awh[k], bh, acc[ns]);
        acc[ns] = MFMA16(awl[k], bh, acc[ns]);
        acc[ns] = MFMA16(awh[k], bl, acc[ns]);
      }
    }
  }

  float bia[4];
  #pragma unroll
  for (int r = 0; r < 4; ++r) bia[r] = bias[o0 + quad*4 + r];

  if (mode == 0){
    float d = pd[0], z = pz[0]; float invd = 1.0f / d;
    #pragma unroll
    for (int ns = 0; ns < 4; ++ns){
      int n = nt*64 + ns*16 + lo16;
      U64c pk;
      #pragma unroll
      for (int r = 0; r < 4; ++r){
        float v = acc[ns][r] + bia[r];
        float xq = fminf(fmaxf(rintf(v*invd) + z, 0.f), 255.f);
        pk.u[r] = f2bf(xq - z);
      }
      *(uint2*)(outT + ((size_t)b*Nn + n)*Cc + o0 + quad*4) = pk.v;
    }
  } else if (mode == 1){
    float d = pd[0], z = pz[0]; float invd = 1.0f / d;
    #pragma unroll
    for (int ns = 0; ns < 4; ++ns){
      int n = nt*64 + ns*16 + lo16;
      #pragma unroll
      for (int r = 0; r < 4; ++r){
        float v = acc[ns][r] + bia[r];
        float xq = fminf(fmaxf(rintf(v*invd) + z, 0.f), 255.f);
        outN[((size_t)b*Cc + o0 + quad*4 + r)*Nn + n] = f2bf(xq - z);
      }
    }
  } else {
    #pragma unroll
    for (int ns = 0; ns < 4; ++ns){
      int n = nt*64 + ns*16 + lo16;
      #pragma unroll
      for (int r = 0; r < 4; ++r){
        size_t a = ((size_t)b*Cc + o0 + quad*4 + r)*Nn + n;
        outF[a] = xres[a] + acc[ns][r] + bia[r];
      }
    }
  }
}

// ------------- Attention pass A: row max / sum-exp (online softmax stats) -------------
__global__ __launch_bounds__(256) void k_attn_stats(const u16* __restrict__ qT, const u16* __restrict__ kT,
                                                    const float* __restrict__ pdq, const float* __restrict__ pdk,
                                                    float* __restrict__ rowM, float* __restrict__ rowL){
  int nt = blockIdx.x, b = blockIdx.y;
  __shared__ u16 Qt[64*256], Kt[64*256];
  int t = threadIdx.x, lane = t & 63, wave = t >> 6;
  int lo16 = lane & 15, quad = lane >> 4;

  const u16* qb = qT + ((size_t)b*Nn + nt*64) * 256;
  for (int id = t; id < 64*32; id += 256){
    int r = id >> 5, ch = id & 31;
    *(uint4*)(Qt + r*256 + ((ch ^ (r & 7)))*8) = *(const uint4*)(qb + (size_t)r*256 + ch*8);
  }
  __syncthreads();
  bf16x8 a[8];
  {
    int ar = wave*16 + lo16;
    #pragma unroll
    for (int k = 0; k < 8; ++k)
      a[k] = *(const bf16x8*)(Qt + ar*256 + (((k*4 + quad) ^ (ar & 7)))*8);
  }
  float sc = pdq[0] * pdk[0] * 0.0625f;
  float mr[4], lr[4];
  #pragma unroll
  for (int r = 0; r < 4; ++r){ mr[r] = -1e30f; lr[r] = 0.f; }

  for (int mt = 0; mt < 64; ++mt){
    __syncthreads();
    const u16* kb = kT + ((size_t)b*Nn + mt*64) * 256;
    for (int id = t; id < 64*32; id += 256){
      int r = id >> 5, ch = id & 31;
      *(uint4*)(Kt + r*256 + ((ch ^ (r & 7)))*8) = *(const uint4*)(kb + (size_t)r*256 + ch*8);
    }
    __syncthreads();
    #pragma unroll
    for (int ms = 0; ms < 4; ++ms){
      f32x4 acc = {0.f,0.f,0.f,0.f};
      int br = ms*16 + lo16;
      #pragma unroll
      for (int k = 0; k < 8; ++k){
        bf16x8 bk_ = *(const bf16x8*)(Kt + br*256 + (((k*4 + quad) ^ (br & 7)))*8);
        acc = MFMA16(a[k], bk_, acc);
      }
      #pragma unroll
      for (int r = 0; r < 4; ++r){
        float v = acc[r] * sc;
        float nm = fmaxf(mr[r], v);
        if (nm > mr[r]){ lr[r] *= __expf(mr[r] - nm); mr[r] = nm; }
        lr[r] += __expf(v - nm);
      }
    }
  }
  #pragma unroll
  for (int msk = 1; msk < 16; msk <<= 1){
    #pragma unroll
    for (int r = 0; r < 4; ++r){
      float om = __shfl_xor(mr[r], msk, 64);
      float ol = __shfl_xor(lr[r], msk, 64);
      float nm = fmaxf(mr[r], om);
      lr[r] = lr[r]*__expf(mr[r] - nm) + ol*__expf(om - nm);
      mr[r] = nm;
    }
  }
  if (lo16 == 0){
    #pragma unroll
    for (int r = 0; r < 4; ++r){
      int n = nt*64 + wave*16 + quad*4 + r;
      rowM[b*Nn + n] = mr[r];
      rowL[b*Nn + n] = lr[r];
    }
  }
}

// ------------- Attention pass A2: recompute S, quantize attn^T -> aq u8 [b][m][n] -------------
__global__ __launch_bounds__(256) void k_attn_quant(const u16* __restrict__ qT, const u16* __restrict__ kT,
                                                    const float* __restrict__ pdq, const float* __restrict__ pdk,
                                                    const float* __restrict__ pdw, const float* __restrict__ pzw,
                                                    const float* __restrict__ rowM, const float* __restrict__ rowL,
                                                    u8* __restrict__ aq){
  int nt = blockIdx.x, b = blockIdx.y;
  __shared__ u16 Qt[64*256], Kt[64*256];
  int t = threadIdx.x, lane = t & 63, wave = t >> 6;
  int lo16 = lane & 15, quad = lane >> 4;

  const u16* qb = qT + ((size_t)b*Nn + nt*64) * 256;
  for (int id = t; id < 64*32; id += 256){
    int r = id >> 5, ch = id & 31;
    *(uint4*)(Qt + r*256 + ((ch ^ (r & 7)))*8) = *(const uint4*)(qb + (size_t)r*256 + ch*8);
  }
  __syncthreads();
  bf16x8 a[8];
  {
    int ar = wave*16 + lo16;
    #pragma unroll
    for (int k = 0; k < 8; ++k)
      a[k] = *(const bf16x8*)(Qt + ar*256 + (((k*4 + quad) ^ (ar & 7)))*8);
  }
  float sc = pdq[0] * pdk[0] * 0.0625f;
  float invdw = 1.0f / pdw[0];
  float zw = pzw[0];
  float Mr[4], Li[4];
  #pragma unroll
  for (int r = 0; r < 4; ++r){
    int n = nt*64 + wave*16 + quad*4 + r;
    Mr[r] = rowM[b*Nn + n];
    Li[r] = 1.0f / rowL[b*Nn + n];
  }

  for (int mt = 0; mt < 64; ++mt){
    __syncthreads();
    const u16* kb = kT + ((size_t)b*Nn + mt*64) * 256;
    for (int id = t; id < 64*32; id += 256){
      int r = id >> 5, ch = id & 31;
      *(uint4*)(Kt + r*256 + ((ch ^ (r & 7)))*8) = *(const uint4*)(kb + (size_t)r*256 + ch*8);
    }
    __syncthreads();
    #pragma unroll
    for (int ms = 0; ms < 4; ++ms){
      f32x4 acc = {0.f,0.f,0.f,0.f};
      int br = ms*16 + lo16;
      #pragma unroll
      for (int k = 0; k < 8; ++k){
        bf16x8 bk_ = *(const bf16x8*)(Kt + br*256 + (((k*4 + quad) ^ (br & 7)))*8);
        acc = MFMA16(a[k], bk_, acc);
      }
      int m = mt*64 + ms*16 + lo16;
      u32 w = 0;
      #pragma unroll
      for (int r = 0; r < 4; ++r){
        float s_ = acc[r] * sc;
        float at = __expf(s_ - Mr[r]) * Li[r];
        float xq = fminf(fmaxf(rintf(at*invdw) + zw, 0.f), 255.f);
        w |= ((u32)(int)xq) << (8*r);
      }
      *(u32*)(aq + (size_t)b*Nn*Nn + (size_t)m*Nn + nt*64 + wave*16 + quad*4) = w;
    }
  }
}

// ------------- PV GEMM: h[c][n] = sum_m V8[c][m] * (aq[m][n]-zw), scaled; out hi/lo [b][n][c] -------------
__global__ __launch_bounds__(256) void k_pv(const u16* __restrict__ v8, const u8* __restrict__ aq,
                                            const float* __restrict__ pdv, const float* __restrict__ pdw,
                                            const float* __restrict__ pzw,
                                            u16* __restrict__ h2hi, u16* __restrict__ h2lo){
  int nt = blockIdx.x, ct = blockIdx.y, b = blockIdx.z;  // tile: 64 c x 128 n
  __shared__ u16 Vt[64*64], Pt[128*64];
  int t = threadIdx.x, lane = t & 63, wave = t >> 6;
  int lo16 = lane & 15, quad = lane >> 4;
  float zw = pzw[0];

  f32x4 zf = {0.f,0.f,0.f,0.f};
  f32x4 acc[8] = {zf,zf,zf,zf,zf,zf,zf,zf};

  const u16* vbase = v8 + ((size_t)(b*Cc + ct*64))*Nn;
  const u8*  abase = aq + (size_t)b*Nn*Nn + nt*128;

  for (int mt = 0; mt < 64; ++mt){
    __syncthreads();
    for (int id = t; id < 64*8; id += 256){
      int r = id >> 3, ch = id & 7;
      *(uint4*)(Vt + r*64 + ((ch ^ (r & 7)))*8) = *(const uint4*)(vbase + (size_t)r*Nn + mt*64 + ch*8);
    }
    for (int id = t; id < 64*32; id += 256){
      int mr = id >> 5, nc = id & 31;
      u32 w = *(const u32*)(abase + (size_t)(mt*64 + mr)*Nn + nc*4);
      #pragma unroll
      for (int u = 0; u < 4; ++u){
        int n = nc*4 + u;
        float pv = (float)((w >> (8*u)) & 255u) - zw;
        Pt[n*64 + (((mr >> 3) ^ (n & 7)))*8 + (mr & 7)] = f2bf(pv);
      }
    }
    __syncthreads();
    #pragma unroll
    for (int k = 0; k < 2; ++k){
      int vr = wave*16 + lo16;
      bf16x8 af = *(const bf16x8*)(Vt + vr*64 + (((k*4 + quad) ^ (vr & 7)))*8);
      #pragma unroll
      for (int ns = 0; ns < 8; ++ns){
        int pr = ns*16 + lo16;
        bf16x8 bf_ = *(const bf16x8*)(Pt + pr*64 + (((k*4 + quad) ^ (pr & 7)))*8);
        acc[ns] = MFMA16(af, bf_, acc[ns]);
      }
    }
  }
  float s = pdv[0] * pdw[0];
  #pragma unroll
  for (int ns = 0; ns < 8; ++ns){
    int n = nt*128 + ns*16 + lo16;
    int c0 = ct*64 + wave*16 + quad*4;
    U64c Uh, Ul;
    #pragma unroll
    for (int r = 0; r < 4; ++r){
      float val = acc[ns][r] * s;
      u16 h = f2bf(val);
      Uh.u[r] = h; Ul.u[r] = f2bf(val - bf2f(h));
    }
    *(uint2*)(h2hi + ((size_t)b*Nn + n)*Cc + c0) = Uh.v;
    *(uint2*)(h2lo + ((size_t)b*Nn + n)*Cc + c0) = Ul.v;
  }
}

extern "C" void kernel_launch(void* const* d_in, const int* in_sizes, int n_in,
                              void* d_out, int out_size, void* d_ws, size_t ws_size,
                              hipStream_t stream){
  (void)in_sizes; (void)n_in; (void)out_size; (void)ws_size;
  const float* x   = (const float*)d_in[0];
  const float* gsc = (const float*)d_in[1];
  const float* gbi = (const float*)d_in[2];
  const float* wq  = (const float*)d_in[3];
  const float* bq  = (const float*)d_in[4];
  const float* wk  = (const float*)d_in[5];
  const float* bk  = (const float*)d_in[6];
  const float* wv  = (const float*)d_in[7];
  const float* bv  = (const float*)d_in[8];
  const float* wp  = (const float*)d_in[9];
  const float* bp  = (const float*)d_in[10];
  const float* dq  = (const float*)d_in[11];
  const float* zq  = (const float*)d_in[12];
  const float* dk  = (const float*)d_in[13];
  const float* zk  = (const float*)d_in[14];
  const float* dv  = (const float*)d_in[15];
  const float* zv  = (const float*)d_in[16];
  const float* dw  = (const float*)d_in[17];
  const float* zw  = (const float*)d_in[18];
  float* out = (float*)d_out;

  const size_t SZT = (size_t)Bb*Nn*Cc;  // 4,194,304 elems
  u16* hT_hi = (u16*)d_ws;
  u16* hT_lo = hT_hi + SZT;
  u16* qT8   = hT_lo + SZT;
  u16* kT8   = qT8 + SZT;
  u16* v8    = kT8 + SZT;
  u16* h2hi  = v8 + SZT;
  u16* h2lo  = h2hi + SZT;
  float* mu   = (float*)(h2lo + SZT);
  float* rs   = mu + 128;
  float* rowM = rs + 128;
  float* rowL = rowM + (size_t)Bb*Nn;
  u8*    aq   = (u8*)(rowL + (size_t)Bb*Nn);
  // total ws use: ~126 MB

  k_gn_stats<<<dim3(Bb*NGRP), 256, 0, stream>>>(x, mu, rs);
  k_gn_apply<<<dim3(Nn/64, Cc/64, Bb), 256, 0, stream>>>(x, gsc, gbi, mu, rs, hT_hi, hT_lo);

  // q, k: quantize + store transposed [n][c]; v: quantize + store natural [c][m]
  k_conv<<<dim3(Nn/64, 4, Bb), 256, 0, stream>>>(wq, hT_hi, hT_lo, bq, dq, zq, qT8, nullptr, nullptr, nullptr, 0);
  k_conv<<<dim3(Nn/64, 4, Bb), 256, 0, stream>>>(wk, hT_hi, hT_lo, bk, dk, zk, kT8, nullptr, nullptr, nullptr, 0);
  k_conv<<<dim3(Nn/64, 4, Bb), 256, 0, stream>>>(wv, hT_hi, hT_lo, bv, dv, zv, nullptr, v8, nullptr, nullptr, 1);

  k_attn_stats<<<dim3(Nn/64, Bb), 256, 0, stream>>>(qT8, kT8, dq, dk, rowM, rowL);
  k_attn_quant<<<dim3(Nn/64, Bb), 256, 0, stream>>>(qT8, kT8, dq, dk, dw, zw, rowM, rowL, aq);

  k_pv<<<dim3(Nn/128, 4, Bb), 256, 0, stream>>>(v8, aq, dv, dw, zw, h2hi, h2lo);

  // proj + residual -> f32 out
  k_conv<<<dim3(Nn/64, 4, Bb), 256, 0, stream>>>(wp, h2hi, h2lo, bp, nullptr, nullptr, nullptr, nullptr, x, out, 2);

  (void)zv;
}

// Round 3
// 433.735 us; speedup vs baseline: 1.8125x; 1.8125x over previous
//
#include <hip/hip_runtime.h>

// QuantAttnBlock on gfx950, round 3: i8 MFMA for QK and PV (quantized values
// are exact signed ints), ones-MFMA trick for the zero-point correction,
// conflict-free XOR-swizzled LDS everywhere, merged attention kernel.

#define Bb 4
#define Cc 256
#define Nn 4096
#define NGRP 32

typedef unsigned short u16;
typedef unsigned int   u32;
typedef unsigned char  u8;
typedef __attribute__((ext_vector_type(8))) short bf16x8;
typedef __attribute__((ext_vector_type(4))) float f32x4;
typedef __attribute__((ext_vector_type(4))) int   i32x4;

#define MFMA_BF16(a,b,c) __builtin_amdgcn_mfma_f32_32x32x16_bf16((a),(b),(c),0,0,0)
#define MFMA16(a,b,c)    __builtin_amdgcn_mfma_f32_16x16x32_bf16((a),(b),(c),0,0,0)
#define MFMA_I8(a,b,c)   __builtin_amdgcn_mfma_i32_16x16x64_i8((a),(b),(c),0,0,0)

static __device__ __forceinline__ u16 f2bf(float x){
  u32 u = __float_as_uint(x);
  u += 0x7fffu + ((u >> 16) & 1u);
  return (u16)(u >> 16);
}
static __device__ __forceinline__ float bf2f(u16 h){ return __uint_as_float(((u32)h) << 16); }

union U64c { u16 u[4]; uint2 v; };

// ---------------- GroupNorm stats ----------------
__global__ __launch_bounds__(256) void k_gn_stats(const float* __restrict__ x,
                                                  float* __restrict__ mu, float* __restrict__ rs){
  int bg = blockIdx.x;
  const float4* p = (const float4*)(x + (size_t)bg * (8 * Nn));
  float s = 0.f, q = 0.f;
  for (int i = threadIdx.x; i < 8*Nn/4; i += 256){
    float4 v = p[i];
    s += v.x + v.y + v.z + v.w;
    q += v.x*v.x + v.y*v.y + v.z*v.z + v.w*v.w;
  }
  __shared__ float rsum[256], rsq[256];
  rsum[threadIdx.x] = s; rsq[threadIdx.x] = q;
  __syncthreads();
  for (int off = 128; off > 0; off >>= 1){
    if (threadIdx.x < off){ rsum[threadIdx.x] += rsum[threadIdx.x+off]; rsq[threadIdx.x] += rsq[threadIdx.x+off]; }
    __syncthreads();
  }
  if (threadIdx.x == 0){
    const float inv = 1.0f / (8*Nn);
    float m = rsum[0]*inv;
    float var = rsq[0]*inv - m*m;
    mu[bg] = m; rs[bg] = rsqrtf(var + 1e-6f);
  }
}

// ------------- GroupNorm apply + transpose -> hT hi/lo [b][n][c] -------------
__global__ __launch_bounds__(256) void k_gn_apply(const float* __restrict__ x,
                                                  const float* __restrict__ gsc, const float* __restrict__ gbi,
                                                  const float* __restrict__ mu, const float* __restrict__ rs,
                                                  u16* __restrict__ hhi, u16* __restrict__ hlo){
  int nt = blockIdx.x, ct = blockIdx.y, b = blockIdx.z;
  int n0 = nt*64, c0 = ct*64;
  __shared__ float yt[64*65];
  __shared__ float sa[64], sb[64];
  int t = threadIdx.x;
  if (t < 64){
    int c = c0 + t;
    int bg = b*NGRP + (c >> 3);
    float a = rs[bg] * gsc[c];
    sa[t] = a;
    sb[t] = gbi[c] - mu[bg]*a;
  }
  __syncthreads();
  #pragma unroll
  for (int j = 0; j < 4; ++j){
    int id = t + j*256;
    int r = id >> 4, cq = id & 15;
    float4 v = *(const float4*)(x + ((size_t)b*Cc + c0 + r)*Nn + n0 + cq*4);
    float a = sa[r], bb = sb[r];
    yt[r*65 + cq*4 + 0] = v.x*a + bb;
    yt[r*65 + cq*4 + 1] = v.y*a + bb;
    yt[r*65 + cq*4 + 2] = v.z*a + bb;
    yt[r*65 + cq*4 + 3] = v.w*a + bb;
  }
  __syncthreads();
  int nl = t >> 2, cg = (t & 3) * 16;
  size_t base = ((size_t)b*Nn + n0 + nl)*Cc + c0 + cg;
  #pragma unroll
  for (int half = 0; half < 2; ++half){
    union { u16 u[8]; uint4 v; } Ph, Pl;
    #pragma unroll
    for (int u = 0; u < 8; ++u){
      float y = yt[(cg + half*8 + u)*65 + nl];
      u16 h = f2bf(y);
      Ph.u[u] = h; Pl.u[u] = f2bf(y - bf2f(h));
    }
    *(uint4*)(hhi + base + half*8) = Ph.v;
    *(uint4*)(hlo + base + half*8) = Pl.v;
  }
}

// ------------- 1x1 conv GEMM (bf16 hi/lo, ~fp32 accurate) -------------
// mode 0: fake-quant -> i8, store [b][n][c] (q,k). mode 1: fake-quant -> i8,
// store [b][c][m] (v). mode 2: residual + bias -> f32 d_out (proj).
__global__ __launch_bounds__(256) void k_conv(const float* __restrict__ W,
                                              const u16* __restrict__ Hhi, const u16* __restrict__ Hlo,
                                              const float* __restrict__ bias,
                                              const float* __restrict__ pd, const float* __restrict__ pz,
                                              u8* __restrict__ outT, u8* __restrict__ outN,
                                              const float* __restrict__ xres, float* __restrict__ outF,
                                              int mode){
  int nt = blockIdx.x, ot = blockIdx.y, b = blockIdx.z;
  __shared__ u16 Lh[64*128], Ll[64*128];
  int t = threadIdx.x, lane = t & 63, wave = t >> 6;
  int lo16 = lane & 15, quad = lane >> 4;
  int o0 = ot*64 + wave*16;

  bf16x8 awh[8], awl[8];
  {
    const float* wb = W + (size_t)(o0 + lo16) * 256;
    #pragma unroll
    for (int k = 0; k < 8; ++k){
      union { u16 u[8]; bf16x8 v; } Wh, Wl;
      #pragma unroll
      for (int u = 0; u < 8; ++u){
        float w = wb[k*32 + quad*8 + u];
        u16 h = f2bf(w);
        Wh.u[u] = h; Wl.u[u] = f2bf(w - bf2f(h));
      }
      awh[k] = Wh.v; awl[k] = Wl.v;
    }
  }
  f32x4 zf = {0.f,0.f,0.f,0.f};
  f32x4 acc[4] = {zf, zf, zf, zf};

  const u16* hb = Hhi + ((size_t)b*Nn + nt*64) * 256;
  const u16* lb = Hlo + ((size_t)b*Nn + nt*64) * 256;
  for (int kc = 0; kc < 2; ++kc){
    __syncthreads();
    for (int id = t; id < 64*16; id += 256){
      int r = id >> 4, ch = id & 15;
      int sw = (ch ^ (r & 7)) * 8;
      *(uint4*)(Lh + r*128 + sw) = *(const uint4*)(hb + (size_t)r*256 + kc*128 + ch*8);
      *(uint4*)(Ll + r*128 + sw) = *(const uint4*)(lb + (size_t)r*256 + kc*128 + ch*8);
    }
    __syncthreads();
    #pragma unroll
    for (int k4 = 0; k4 < 4; ++k4){
      int k = kc*4 + k4;
      #pragma unroll
      for (int ns = 0; ns < 4; ++ns){
        int r = ns*16 + lo16;
        int ch = ((k4*4 + quad) ^ (r & 7)) * 8;
        bf16x8 bh = *(const bf16x8*)(Lh + r*128 + ch);
        bf16x8 bl = *(const bf16x8*)(Ll + r*128 + ch);
        acc[ns] = MFMA16(awh[k], bh, acc[ns]);
        acc[ns] = MFMA16(awl[k], bh, acc[ns]);
        acc[ns] = MFMA16(awh[k], bl, acc[ns]);
      }
    }
  }

  float bia[4];
  #pragma unroll
  for (int r = 0; r < 4; ++r) bia[r] = bias[o0 + quad*4 + r];

  if (mode == 0){
    float z = pz[0]; float invd = 1.0f / pd[0];
    #pragma unroll
    for (int ns = 0; ns < 4; ++ns){
      int n = nt*64 + ns*16 + lo16;
      u32 w = 0;
      #pragma unroll
      for (int r = 0; r < 4; ++r){
        float v = acc[ns][r] + bia[r];
        float xq = fminf(fmaxf(rintf(v*invd) + z, 0.f), 255.f);
        int qi = (int)rintf(xq - z);
        w |= ((u32)(qi & 255)) << (8*r);
      }
      *(u32*)(outT + ((size_t)b*Nn + n)*Cc + o0 + quad*4) = w;
    }
  } else if (mode == 1){
    float z = pz[0]; float invd = 1.0f / pd[0];
    #pragma unroll
    for (int ns = 0; ns < 4; ++ns){
      int n = nt*64 + ns*16 + lo16;
      #pragma unroll
      for (int r = 0; r < 4; ++r){
        float v = acc[ns][r] + bia[r];
        float xq = fminf(fmaxf(rintf(v*invd) + z, 0.f), 255.f);
        int qi = (int)rintf(xq - z);
        outN[((size_t)b*Cc + o0 + quad*4 + r)*Nn + n] = (u8)(qi & 255);
      }
    }
  } else {
    #pragma unroll
    for (int ns = 0; ns < 4; ++ns){
      int n = nt*64 + ns*16 + lo16;
      #pragma unroll
      for (int r = 0; r < 4; ++r){
        size_t a = ((size_t)b*Cc + o0 + quad*4 + r)*Nn + n;
        outF[a] = xres[a] + acc[ns][r] + bia[r];
      }
    }
  }
}

static __device__ __forceinline__ void stage64x256(u8* dst, const u8* __restrict__ src, int t){
  #pragma unroll
  for (int j = 0; j < 4; ++j){
    int id = t + j*256; int r = id >> 4, ch = id & 15;
    *(uint4*)(dst + r*256 + ((ch ^ (r & 15)) << 4)) = *(const uint4*)(src + r*256 + ch*16);
  }
}

// ------------- Merged attention: QK (i8) -> online softmax stats -> requantize
// attn^T -> aq i8 [b][m][n] (bytes pre-shifted by -128 via ^0x80) -------------
__global__ __launch_bounds__(256) void k_attn(const u8* __restrict__ qT8, const u8* __restrict__ kT8,
                                              const float* __restrict__ pdq, const float* __restrict__ pdk,
                                              const float* __restrict__ pdw, const float* __restrict__ pzw,
                                              u8* __restrict__ aq){
  int nt = blockIdx.x, b = blockIdx.y;
  __shared__ u8 Qt[64*256], Kt[64*256];
  int t = threadIdx.x, lane = t & 63, wave = t >> 6;
  int lo16 = lane & 15, quad = lane >> 4;

  stage64x256(Qt, qT8 + ((size_t)b*Nn + nt*64)*256, t);
  __syncthreads();
  i32x4 a[4];
  {
    int ar = wave*16 + lo16;
    #pragma unroll
    for (int k = 0; k < 4; ++k)
      a[k] = *(const i32x4*)(Qt + ar*256 + (((k*4 + quad) ^ (ar & 15)) << 4));
  }
  float sc = pdq[0] * pdk[0] * 0.0625f;
  float mr[4], lr[4];
  #pragma unroll
  for (int r = 0; r < 4; ++r){ mr[r] = -3e38f; lr[r] = 0.f; }

  const u8* kbase = kT8 + (size_t)b*Nn*256;
  for (int mt = 0; mt < 64; ++mt){
    __syncthreads();
    stage64x256(Kt, kbase + (size_t)mt*64*256, t);
    __syncthreads();
    #pragma unroll
    for (int ms = 0; ms < 4; ++ms){
      i32x4 acc = {0,0,0,0};
      int br = ms*16 + lo16;
      #pragma unroll
      for (int k = 0; k < 4; ++k){
        i32x4 bk_ = *(const i32x4*)(Kt + br*256 + (((k*4 + quad) ^ (br & 15)) << 4));
        acc = MFMA_I8(a[k], bk_, acc);
      }
      #pragma unroll
      for (int r = 0; r < 4; ++r){
        float v = (float)acc[r] * sc;
        float nm = fmaxf(mr[r], v);
        if (nm > mr[r]){ lr[r] *= __expf(mr[r] - nm); mr[r] = nm; }
        lr[r] += __expf(v - nm);
      }
    }
  }
  #pragma unroll
  for (int msk = 1; msk < 16; msk <<= 1){
    #pragma unroll
    for (int r = 0; r < 4; ++r){
      float om = __shfl_xor(mr[r], msk, 64);
      float ol = __shfl_xor(lr[r], msk, 64);
      float nm = fmaxf(mr[r], om);
      lr[r] = lr[r]*__expf(mr[r] - nm) + ol*__expf(om - nm);
      mr[r] = nm;
    }
  }
  float Mr[4], Li[4];
  #pragma unroll
  for (int r = 0; r < 4; ++r){ Mr[r] = mr[r]; Li[r] = 1.0f / lr[r]; }
  float invdw = 1.0f / pdw[0];
  float zw = pzw[0];
  u8* aqb = aq + (size_t)b*Nn*Nn + nt*64 + wave*16 + quad*4;

  for (int mt = 0; mt < 64; ++mt){
    __syncthreads();
    stage64x256(Kt, kbase + (size_t)mt*64*256, t);
    __syncthreads();
    #pragma unroll
    for (int ms = 0; ms < 4; ++ms){
      i32x4 acc = {0,0,0,0};
      int br = ms*16 + lo16;
      #pragma unroll
      for (int k = 0; k < 4; ++k){
        i32x4 bk_ = *(const i32x4*)(Kt + br*256 + (((k*4 + quad) ^ (br & 15)) << 4));
        acc = MFMA_I8(a[k], bk_, acc);
      }
      int m = mt*64 + ms*16 + lo16;
      u32 w = 0;
      #pragma unroll
      for (int r = 0; r < 4; ++r){
        float s_ = (float)acc[r] * sc;
        float at = __expf(s_ - Mr[r]) * Li[r];
        float xq = fminf(fmaxf(rintf(at*invdw) + zw, 0.f), 255.f);
        w |= ((u32)(int)xq) << (8*r);
      }
      *(u32*)(aqb + (size_t)m*Nn) = w ^ 0x80808080u;
    }
  }
}

// ------------- PV GEMM (i8): h[c][n] = dv*dw*(sum V*(aq-128) + (128-zw)*sumV) -------------
__global__ __launch_bounds__(256) void k_pv(const u8* __restrict__ v8, const u8* __restrict__ aq,
                                            const float* __restrict__ pdv, const float* __restrict__ pdw,
                                            const float* __restrict__ pzw,
                                            u16* __restrict__ h2hi, u16* __restrict__ h2lo){
  int nt = blockIdx.x, ct = blockIdx.y, b = blockIdx.z;  // tile: 64 c x 128 n
  __shared__ u8 Vt[64*64];
  __shared__ u8 Pt[128*64];
  int t = threadIdx.x, lane = t & 63, wave = t >> 6;
  int lo16 = lane & 15, quad = lane >> 4;

  i32x4 zi = {0,0,0,0};
  i32x4 acc[8] = {zi,zi,zi,zi,zi,zi,zi,zi};
  i32x4 accO = zi;
  const i32x4 ones = {0x01010101,0x01010101,0x01010101,0x01010101};

  const u8* vbase = v8 + ((size_t)(b*Cc + ct*64))*Nn;
  const u8* abase = aq + (size_t)b*Nn*Nn + nt*128;
  int n4 = t & 31, mg = t >> 5;

  for (int mt = 0; mt < 64; ++mt){
    __syncthreads();
    {
      int c = t >> 2, ch = t & 3;
      *(uint4*)(Vt + c*64 + ((ch ^ (c & 3)) << 4)) = *(const uint4*)(vbase + (size_t)c*Nn + mt*64 + ch*16);
    }
    {
      u32 w[8];
      const u8* ab = abase + (size_t)(mt*64 + mg*8)*Nn + n4*4;
      #pragma unroll
      for (int j = 0; j < 8; ++j) w[j] = *(const u32*)(ab + (size_t)j*Nn);
      #pragma unroll
      for (int r = 0; r < 4; ++r){
        u32 sel = 0x0C0C0000u | ((u32)(4+r) << 8) | (u32)r;
        u32 x0 = __builtin_amdgcn_perm(w[1], w[0], sel);
        u32 y0 = __builtin_amdgcn_perm(w[3], w[2], sel);
        u32 lo = __builtin_amdgcn_perm(y0, x0, 0x05040100u);
        u32 x1 = __builtin_amdgcn_perm(w[5], w[4], sel);
        u32 y1 = __builtin_amdgcn_perm(w[7], w[6], sel);
        u32 hi = __builtin_amdgcn_perm(y1, x1, 0x05040100u);
        int n = n4*4 + r;
        u32* dst = (u32*)(Pt + n*64 + (((mg >> 1) ^ (n4 & 3)) << 4) + ((mg & 1) << 3));
        dst[0] = lo; dst[1] = hi;
      }
    }
    __syncthreads();
    int cr = wave*16 + lo16;
    i32x4 af = *(const i32x4*)(Vt + cr*64 + ((quad ^ (cr & 3)) << 4));
    accO = MFMA_I8(af, ones, accO);
    #pragma unroll
    for (int ns = 0; ns < 8; ++ns){
      int pr = ns*16 + lo16;
      i32x4 bf_ = *(const i32x4*)(Pt + pr*64 + ((quad ^ ((pr >> 2) & 3)) << 4));
      acc[ns] = MFMA_I8(af, bf_, acc[ns]);
    }
  }
  float s = pdv[0] * pdw[0];
  float corr = s * (128.0f - pzw[0]);
  #pragma unroll
  for (int ns = 0; ns < 8; ++ns){
    int n = nt*128 + ns*16 + lo16;
    int c0 = ct*64 + wave*16 + quad*4;
    U64c Uh, Ul;
    #pragma unroll
    for (int r = 0; r < 4; ++r){
      float val = s*(float)acc[ns][r] + corr*(float)accO[r];
      u16 h = f2bf(val);
      Uh.u[r] = h; Ul.u[r] = f2bf(val - bf2f(h));
    }
    *(uint2*)(h2hi + ((size_t)b*Nn + n)*Cc + c0) = Uh.v;
    *(uint2*)(h2lo + ((size_t)b*Nn + n)*Cc + c0) = Ul.v;
  }
}

extern "C" void kernel_launch(void* const* d_in, const int* in_sizes, int n_in,
                              void* d_out, int out_size, void* d_ws, size_t ws_size,
                              hipStream_t stream){
  (void)in_sizes; (void)n_in; (void)out_size; (void)ws_size;
  const float* x   = (const float*)d_in[0];
  const float* gsc = (const float*)d_in[1];
  const float* gbi = (const float*)d_in[2];
  const float* wq  = (const float*)d_in[3];
  const float* bq  = (const float*)d_in[4];
  const float* wk  = (const float*)d_in[5];
  const float* bk  = (const float*)d_in[6];
  const float* wv  = (const float*)d_in[7];
  const float* bv  = (const float*)d_in[8];
  const float* wp  = (const float*)d_in[9];
  const float* bp  = (const float*)d_in[10];
  const float* dq  = (const float*)d_in[11];
  const float* zq  = (const float*)d_in[12];
  const float* dk  = (const float*)d_in[13];
  const float* zk  = (const float*)d_in[14];
  const float* dv  = (const float*)d_in[15];
  const float* zv  = (const float*)d_in[16];
  const float* dw  = (const float*)d_in[17];
  const float* zw  = (const float*)d_in[18];
  float* out = (float*)d_out;

  const size_t SZT = (size_t)Bb*Nn*Cc;  // 4,194,304 elems
  u16* hT_hi = (u16*)d_ws;
  u16* hT_lo = hT_hi + SZT;
  u16* h2hi  = hT_lo + SZT;
  u16* h2lo  = h2hi + SZT;
  u8*  qT8   = (u8*)(h2lo + SZT);
  u8*  kT8   = qT8 + SZT;
  u8*  v8    = kT8 + SZT;
  u8*  aq    = v8 + SZT;
  float* mu  = (float*)(aq + (size_t)Bb*Nn*Nn);
  float* rs  = mu + 128;
  // total ws use: ~113 MB

  k_gn_stats<<<dim3(Bb*NGRP), 256, 0, stream>>>(x, mu, rs);
  k_gn_apply<<<dim3(Nn/64, Cc/64, Bb), 256, 0, stream>>>(x, gsc, gbi, mu, rs, hT_hi, hT_lo);

  k_conv<<<dim3(Nn/64, 4, Bb), 256, 0, stream>>>(wq, hT_hi, hT_lo, bq, dq, zq, qT8, nullptr, nullptr, nullptr, 0);
  k_conv<<<dim3(Nn/64, 4, Bb), 256, 0, stream>>>(wk, hT_hi, hT_lo, bk, dk, zk, kT8, nullptr, nullptr, nullptr, 0);
  k_conv<<<dim3(Nn/64, 4, Bb), 256, 0, stream>>>(wv, hT_hi, hT_lo, bv, dv, zv, nullptr, v8, nullptr, nullptr, 1);

  k_attn<<<dim3(Nn/64, Bb), 256, 0, stream>>>(qT8, kT8, dq, dk, dw, zw, aq);

  k_pv<<<dim3(Nn/128, 4, Bb), 256, 0, stream>>>(v8, aq, dv, dw, zw, h2hi, h2lo);

  k_conv<<<dim3(Nn/64, 4, Bb), 256, 0, stream>>>(wp, h2hi, h2lo, bp, nullptr, nullptr, nullptr, nullptr, x, out, 2);
}